// Round 5
// baseline (812.866 us; speedup 1.0000x reference)
//
#include <hip/hip_runtime.h>
#include <hip/hip_cooperative_groups.h>
#include <math.h>

namespace cg = cooperative_groups;

#define NNODES 6000
#define NEDGES 192000
#define DIN 512
#define HDIM 128
#define EOS 1e-10f

static const size_t NN = (size_t)NNODES * (size_t)NNODES;

typedef float vfloat4 __attribute__((ext_vector_type(4)));

// ---------------------------------------------------------------------------
// One cooperative kernel, 5 phases separated by grid.sync():
//  P0: zero adj_lp/adj_hp (288 MB) + winner/unnorm (144 MB) + deg scratch,
//      AND embed g[i] = dot(relu(feat[i]@w_emb+b_emb), 0.5*(wA+wB)) + b/2
//      (independent of the zero — overlapped in the same phase).
//  P1: per-edge gate weights + last-write-wins winner via atomicMax(e+1).
//  P2: dedup'd weighted degree sums (winner edges only — numpy set semantics).
//  P3: inv-sqrt degrees + diagonal defaults.
//  P4: winner edges write normalized adjacency cells + unnorm=1.0.
// ---------------------------------------------------------------------------
__global__ __launch_bounds__(256, 3) void fused_kernel(
    const float* __restrict__ feat, const int* __restrict__ edges,
    const float* __restrict__ w_emb, const float* __restrict__ b_emb,
    const float* __restrict__ w_mlp, const float* __restrict__ b_mlp,
    const float* __restrict__ noise, float* __restrict__ adj_lp,
    float* __restrict__ adj_hp, float* __restrict__ w_lp,
    float* __restrict__ w_hp, float* __restrict__ unnorm,
    float* __restrict__ deg_lp, float* __restrict__ deg_hp,
    float* __restrict__ inv_lp, float* __restrict__ inv_hp,
    float* __restrict__ g) {
  cg::grid_group grid = cg::this_grid();
  const int tid = threadIdx.x;
  const size_t gtid = (size_t)blockIdx.x * blockDim.x + tid;
  const size_t gstride = (size_t)gridDim.x * blockDim.x;

  __shared__ float sf[16 * DIN];  // 32 KB: 16 feature rows per embed group

  // ---- P0a: zero sweep (grid-stride, nontemporal 16B stores) ----
  {
    const vfloat4 z = {0.f, 0.f, 0.f, 0.f};
    vfloat4* a = (vfloat4*)adj_lp;  // adj_lp + adj_hp contiguous: 2*NN floats
    for (size_t k = gtid; k < (2 * NN) / 4; k += gstride)
      __builtin_nontemporal_store(z, a + k);
    vfloat4* b = (vfloat4*)unnorm;  // doubles as int winner array
    for (size_t k = gtid; k < NN / 4; k += gstride)
      __builtin_nontemporal_store(z, b + k);
    vfloat4* c = (vfloat4*)deg_lp;  // deg_lp + deg_hp contiguous: 2*N floats
    for (size_t k = gtid; k < (2 * NNODES) / 4; k += gstride) c[k] = z;
  }

  // ---- P0b: embed.  375 groups x 16 nodes; trip count block-uniform so
  // __syncthreads() is legal.  Wave w handles nodes [bg*16+4w, +4); lane t
  // handles h=t and h=t+64; LDS rows read as broadcast float4. ----
  for (int bg = blockIdx.x; bg < NNODES / 16; bg += gridDim.x) {
    const float4* f4 = (const float4*)(feat + (size_t)bg * 16 * DIN);
    float4* s4 = (float4*)sf;
#pragma unroll
    for (int k = 0; k < 8; ++k) s4[k * 256 + tid] = f4[k * 256 + tid];
    __syncthreads();

    const int wave = tid >> 6, lane = tid & 63;
    const float* sw = sf + wave * (4 * DIN);
    const int h0 = lane, h1 = lane + 64;
    float acc0[4], acc1[4];
    const float bb0 = b_emb[h0], bb1 = b_emb[h1];
#pragma unroll
    for (int n = 0; n < 4; ++n) { acc0[n] = bb0; acc1[n] = bb1; }

    for (int d = 0; d < DIN; d += 4) {
      const float w00 = w_emb[(d + 0) * HDIM + h0];
      const float w01 = w_emb[(d + 1) * HDIM + h0];
      const float w02 = w_emb[(d + 2) * HDIM + h0];
      const float w03 = w_emb[(d + 3) * HDIM + h0];
      const float w10 = w_emb[(d + 0) * HDIM + h1];
      const float w11 = w_emb[(d + 1) * HDIM + h1];
      const float w12 = w_emb[(d + 2) * HDIM + h1];
      const float w13 = w_emb[(d + 3) * HDIM + h1];
#pragma unroll
      for (int n = 0; n < 4; ++n) {
        const float4 f = *(const float4*)&sw[n * DIN + d];
        acc0[n] += f.x * w00;
        acc0[n] += f.y * w01;
        acc0[n] += f.z * w02;
        acc0[n] += f.w * w03;
        acc1[n] += f.x * w10;
        acc1[n] += f.y * w11;
        acc1[n] += f.z * w12;
        acc1[n] += f.w * w13;
      }
    }

    const float wv0 = 0.5f * (w_mlp[h0] + w_mlp[HDIM + h0]);
    const float wv1 = 0.5f * (w_mlp[h1] + w_mlp[HDIM + h1]);
    const float half_b = 0.5f * b_mlp[0];
    const int node0 = bg * 16 + wave * 4;
#pragma unroll
    for (int n = 0; n < 4; ++n) {
      float v = fmaxf(acc0[n], 0.0f) * wv0 + fmaxf(acc1[n], 0.0f) * wv1;
#pragma unroll
      for (int off = 32; off > 0; off >>= 1) v += __shfl_down(v, off, 64);
      if (lane == 0) g[node0 + n] = v + half_b;  // b_mlp folded: raw=g[u]+g[v]
    }
    __syncthreads();  // protect LDS before next bg iteration re-stages
  }

  grid.sync();

  // ---- P1: gate weights + winner resolution ----
  for (size_t e = gtid; e < NEDGES; e += gstride) {
    const int u = edges[e];
    const int v = edges[NEDGES + e];
    const float x = noise[e] + g[u] + g[v];  // TEMP == 1
    const float wl = 1.0f / (1.0f + expf(-x));
    w_lp[e] = wl;
    w_hp[e] = 1.0f - wl;
    atomicMax((int*)unnorm + ((size_t)u * NNODES + v), (int)e + 1);
  }

  grid.sync();

  // ---- P2: dedup'd degree sums ----
  for (size_t e = gtid; e < NEDGES; e += gstride) {
    const int u = edges[e];
    const int v = edges[NEDGES + e];
    if (((const int*)unnorm)[(size_t)u * NNODES + v] != (int)e + 1) continue;
    atomicAdd(&deg_lp[u], w_lp[e]);
    atomicAdd(&deg_hp[u], w_hp[e]);
  }

  grid.sync();

  // ---- P3: inv-sqrt degrees (+1 eye) + diagonal defaults.
  // adj_lp[i,i] = inv^2 (eye term); adj_hp[i,i] = 1 (mask=0 default).
  // Self-loop winner edges override both in P4. ----
  for (size_t i = gtid; i < NNODES; i += gstride) {
    const float il = 1.0f / (sqrtf(deg_lp[i] + 1.0f) + EOS);
    const float ih = 1.0f / (sqrtf(deg_hp[i] + 1.0f) + EOS);
    inv_lp[i] = il;
    inv_hp[i] = ih;
    const size_t dg = (size_t)i * NNODES + i;
    adj_lp[dg] = il * il;
    adj_hp[dg] = 1.0f;
  }

  grid.sync();

  // ---- P4: winner edges write adjacency cells + unnorm=1.0.
  // Race note: only the winner writes unnorm[cell]=1.0f; dup threads read
  // either winner id (!= their e+1) or 1.0f bits (1065353216 > NEDGES) —
  // both correctly skip. ----
  for (size_t e = gtid; e < NEDGES; e += gstride) {
    const int u = edges[e];
    const int v = edges[NEDGES + e];
    const size_t cell = (size_t)u * NNODES + v;
    if (((const int*)unnorm)[cell] != (int)e + 1) continue;
    const float wl = w_lp[e];
    const float wh = w_hp[e];
    const float il = inv_lp[u] * inv_lp[v];
    const float ih = inv_hp[u] * inv_hp[v];
    if (u == v) {
      adj_lp[cell] = (wl + 1.0f) * il;
      adj_hp[cell] = 1.0f - (wh + 1.0f) * ih;
    } else {
      adj_lp[cell] = wl * il;
      adj_hp[cell] = -wh * ih;
    }
    unnorm[cell] = 1.0f;
  }
}

extern "C" void kernel_launch(void* const* d_in, const int* in_sizes, int n_in,
                              void* d_out, int out_size, void* d_ws,
                              size_t ws_size, hipStream_t stream) {
  const float* feat  = (const float*)d_in[0];
  const int*   edges = (const int*)d_in[1];
  const float* w_emb = (const float*)d_in[2];
  const float* b_emb = (const float*)d_in[3];
  const float* w_mlp = (const float*)d_in[4];
  const float* b_mlp = (const float*)d_in[5];
  const float* noise = (const float*)d_in[6];

  float* out    = (float*)d_out;
  float* adj_lp = out;            // [N,N]
  float* adj_hp = out + NN;       // [N,N]
  float* w_lp   = out + 2 * NN;   // [E] (fully overwritten; not zeroed)
  float* w_hp   = w_lp + NEDGES;  // [E] (fully overwritten; not zeroed)
  float* unnorm = w_hp + NEDGES;  // [N,N] (doubles as int winner array)

  float* deg_lp = (float*)d_ws;     // [N]
  float* deg_hp = deg_lp + NNODES;  // [N]
  float* inv_lp = deg_hp + NNODES;  // [N]
  float* inv_hp = inv_lp + NNODES;  // [N]
  float* g      = inv_hp + NNODES;  // [N]

  // Co-residency-safe grid for cooperative launch (host-only query; no
  // stream ops — graph-capture safe).  Expect 3 blocks/CU -> 768 blocks.
  int bpc = 0;
  hipOccupancyMaxActiveBlocksPerMultiprocessor(&bpc, fused_kernel, 256, 0);
  int nblk = bpc * 256;
  if (nblk > 768) nblk = 768;

  void* kargs[] = {(void*)&feat,   (void*)&edges,  (void*)&w_emb,
                   (void*)&b_emb,  (void*)&w_mlp,  (void*)&b_mlp,
                   (void*)&noise,  (void*)&adj_lp, (void*)&adj_hp,
                   (void*)&w_lp,   (void*)&w_hp,   (void*)&unnorm,
                   (void*)&deg_lp, (void*)&deg_hp, (void*)&inv_lp,
                   (void*)&inv_hp, (void*)&g};
  hipLaunchCooperativeKernel(fused_kernel, dim3(nblk), dim3(256), kargs, 0,
                             stream);
}

// Round 6
// 609.801 us; speedup vs baseline: 1.3330x; 1.3330x over previous
//
#include <hip/hip_runtime.h>
#include <math.h>

#define NNODES 6000
#define NEDGES 192000
#define DIN 512
#define HDIM 128
#define EOS 1e-10f

#define HSLOTS (1 << 20)   // 1M hash slots, load factor ~0.18
#define HMASK (HSLOTS - 1)

static const size_t NN = (size_t)NNODES * (size_t)NNODES;

__device__ __forceinline__ unsigned hash_cell(unsigned cell) {
  return (cell * 2654435761u >> 11) & HMASK;
}

// ---------------------------------------------------------------------------
// Zero: adj_lp+adj_hp (288 MB) + unnorm (144 MB) + hash keys/vals (8 MB) +
// deg scratch.  Plain float4 stores (nt stores measured ~1 TB/s in R5 —
// dropped), 8192 blocks -> expect ~5.5-6 TB/s like the runtime fill.
// ---------------------------------------------------------------------------
__global__ __launch_bounds__(256) void zero_kernel(
    float4* __restrict__ a, size_t na,      // adj_lp..adj_hp
    float4* __restrict__ b, size_t nb,      // unnorm
    float4* __restrict__ c, size_t nc) {    // hash + deg (contiguous in ws)
  const size_t stride = (size_t)gridDim.x * blockDim.x;
  const size_t i = (size_t)blockIdx.x * blockDim.x + threadIdx.x;
  const float4 z = make_float4(0.f, 0.f, 0.f, 0.f);
  for (size_t k = i; k < na; k += stride) a[k] = z;
  for (size_t k = i; k < nb; k += stride) b[k] = z;
  for (size_t k = i; k < nc; k += stride) c[k] = z;
}

// ---------------------------------------------------------------------------
// g[i] = dot(relu(feat[i] @ w_emb + b_emb), wv) + 0.5*b_mlp,
// wv[h] = 0.5*(w_mlp[h]+w_mlp[H+h]).  One wave per block, 8 nodes per wave
// (halves aggregate w_emb cache traffic vs 4), lane t handles h=t, t+64.
// ---------------------------------------------------------------------------
__global__ __launch_bounds__(64) void embed_g_kernel(
    const float* __restrict__ feat, const float* __restrict__ w_emb,
    const float* __restrict__ b_emb, const float* __restrict__ w_mlp,
    const float* __restrict__ b_mlp, float* __restrict__ g) {
  __shared__ float sf[8 * DIN];  // 16 KB
  const int t = threadIdx.x;     // 0..63
  const int nb = blockIdx.x * 8;

  // stage 8 feature rows: 1024 float4, 16 per thread
  const float4* f4 = (const float4*)(feat + (size_t)nb * DIN);
  float4* s4 = (float4*)sf;
#pragma unroll
  for (int k = 0; k < 16; ++k) s4[k * 64 + t] = f4[k * 64 + t];
  __syncthreads();

  const int h0 = t, h1 = t + 64;
  float acc0[8], acc1[8];
  const float b0 = b_emb[h0], b1 = b_emb[h1];
#pragma unroll
  for (int n = 0; n < 8; ++n) { acc0[n] = b0; acc1[n] = b1; }

  for (int d = 0; d < DIN; d += 4) {
    const float w00 = w_emb[(d + 0) * HDIM + h0];
    const float w01 = w_emb[(d + 1) * HDIM + h0];
    const float w02 = w_emb[(d + 2) * HDIM + h0];
    const float w03 = w_emb[(d + 3) * HDIM + h0];
    const float w10 = w_emb[(d + 0) * HDIM + h1];
    const float w11 = w_emb[(d + 1) * HDIM + h1];
    const float w12 = w_emb[(d + 2) * HDIM + h1];
    const float w13 = w_emb[(d + 3) * HDIM + h1];
#pragma unroll
    for (int n = 0; n < 8; ++n) {
      const float4 f = *(const float4*)&sf[n * DIN + d];
      acc0[n] += f.x * w00;
      acc0[n] += f.y * w01;
      acc0[n] += f.z * w02;
      acc0[n] += f.w * w03;
      acc1[n] += f.x * w10;
      acc1[n] += f.y * w11;
      acc1[n] += f.z * w12;
      acc1[n] += f.w * w13;
    }
  }

  const float wv0 = 0.5f * (w_mlp[h0] + w_mlp[HDIM + h0]);
  const float wv1 = 0.5f * (w_mlp[h1] + w_mlp[HDIM + h1]);
  const float half_b = 0.5f * b_mlp[0];
#pragma unroll
  for (int n = 0; n < 8; ++n) {
    float v = fmaxf(acc0[n], 0.0f) * wv0 + fmaxf(acc1[n], 0.0f) * wv1;
#pragma unroll
    for (int off = 32; off > 0; off >>= 1) v += __shfl_down(v, off, 64);
    if (t == 0) g[nb + n] = v + half_b;  // b_mlp folded: raw = g[u]+g[v]
  }
}

// ---------------------------------------------------------------------------
// Pass A: gate weights + last-write-wins winner into the L2-resident hash
// (open addressing: claim slot by key via atomicCAS, then atomicMax(e+1)).
// ---------------------------------------------------------------------------
__global__ __launch_bounds__(256) void edge_weights_kernel(
    const int* __restrict__ edges, const float* __restrict__ g,
    const float* __restrict__ noise, float* __restrict__ w_lp,
    float* __restrict__ w_hp, int* __restrict__ hkeys,
    int* __restrict__ hvals) {
  const int e = blockIdx.x * blockDim.x + threadIdx.x;  // grid == NEDGES
  const int u = edges[e];
  const int v = edges[NEDGES + e];
  const float x = noise[e] + g[u] + g[v];  // TEMP == 1, b_mlp folded in g
  const float wl = 1.0f / (1.0f + expf(-x));
  w_lp[e] = wl;
  w_hp[e] = 1.0f - wl;

  const unsigned cell = (unsigned)u * NNODES + (unsigned)v;
  unsigned idx = hash_cell(cell);
  const int key = (int)cell + 1;
  while (true) {
    const int k = atomicCAS(&hkeys[idx], 0, key);
    if (k == 0 || k == key) { atomicMax(&hvals[idx], e + 1); break; }
    idx = (idx + 1) & HMASK;
  }
}

__device__ __forceinline__ int hash_winner(const int* __restrict__ hkeys,
                                           const int* __restrict__ hvals,
                                           unsigned cell) {
  unsigned idx = hash_cell(cell);
  const int key = (int)cell + 1;
  while (hkeys[idx] != key) idx = (idx + 1) & HMASK;
  return hvals[idx];
}

// ---------------------------------------------------------------------------
// Pass B: dedup'd degree sums (winner edges only — numpy set semantics).
// ---------------------------------------------------------------------------
__global__ __launch_bounds__(256) void edge_deg_kernel(
    const int* __restrict__ edges, const float* __restrict__ w_lp,
    const float* __restrict__ w_hp, const int* __restrict__ hkeys,
    const int* __restrict__ hvals, float* __restrict__ deg_lp,
    float* __restrict__ deg_hp) {
  const int e = blockIdx.x * blockDim.x + threadIdx.x;
  const int u = edges[e];
  const int v = edges[NEDGES + e];
  if (hash_winner(hkeys, hvals, (unsigned)u * NNODES + (unsigned)v) != e + 1)
    return;
  atomicAdd(&deg_lp[u], w_lp[e]);
  atomicAdd(&deg_hp[u], w_hp[e]);
}

// ---------------------------------------------------------------------------
// Pass C: inv-sqrt degrees (+1 eye) + diagonal defaults.
// adj_lp[i,i] = inv^2 (eye); adj_hp[i,i] = 1 (mask=0 default).  Self-loop
// winner edges override both in pass D.
// ---------------------------------------------------------------------------
__global__ __launch_bounds__(256) void node_inv_kernel(
    const float* __restrict__ deg_lp, const float* __restrict__ deg_hp,
    float* __restrict__ inv_lp, float* __restrict__ inv_hp,
    float* __restrict__ adj_lp, float* __restrict__ adj_hp) {
  const int i = blockIdx.x * blockDim.x + threadIdx.x;
  if (i >= NNODES) return;
  const float il = 1.0f / (sqrtf(deg_lp[i] + 1.0f) + EOS);
  const float ih = 1.0f / (sqrtf(deg_hp[i] + 1.0f) + EOS);
  inv_lp[i] = il;
  inv_hp[i] = ih;
  const size_t dg = (size_t)i * NNODES + i;
  adj_lp[dg] = il * il;
  adj_hp[dg] = 1.0f;
}

// ---------------------------------------------------------------------------
// Pass D: winner edges write adjacency cells + unnorm=1.0 (single write per
// occupied cell — no races, winners are unique per cell).
// ---------------------------------------------------------------------------
__global__ __launch_bounds__(256) void edge_write_kernel(
    const int* __restrict__ edges, const float* __restrict__ w_lp,
    const float* __restrict__ w_hp, const float* __restrict__ inv_lp,
    const float* __restrict__ inv_hp, const int* __restrict__ hkeys,
    const int* __restrict__ hvals, float* __restrict__ adj_lp,
    float* __restrict__ adj_hp, float* __restrict__ unnorm) {
  const int e = blockIdx.x * blockDim.x + threadIdx.x;
  const int u = edges[e];
  const int v = edges[NEDGES + e];
  const unsigned cell32 = (unsigned)u * NNODES + (unsigned)v;
  if (hash_winner(hkeys, hvals, cell32) != e + 1) return;
  const size_t cell = (size_t)u * NNODES + v;
  const float wl = w_lp[e];
  const float wh = w_hp[e];
  const float il = inv_lp[u] * inv_lp[v];
  const float ih = inv_hp[u] * inv_hp[v];
  if (u == v) {
    adj_lp[cell] = (wl + 1.0f) * il;
    adj_hp[cell] = 1.0f - (wh + 1.0f) * ih;
  } else {
    adj_lp[cell] = wl * il;
    adj_hp[cell] = -wh * ih;
  }
  unnorm[cell] = 1.0f;
}

extern "C" void kernel_launch(void* const* d_in, const int* in_sizes, int n_in,
                              void* d_out, int out_size, void* d_ws,
                              size_t ws_size, hipStream_t stream) {
  const float* feat  = (const float*)d_in[0];
  const int*   edges = (const int*)d_in[1];
  const float* w_emb = (const float*)d_in[2];
  const float* b_emb = (const float*)d_in[3];
  const float* w_mlp = (const float*)d_in[4];
  const float* b_mlp = (const float*)d_in[5];
  const float* noise = (const float*)d_in[6];

  float* out    = (float*)d_out;
  float* adj_lp = out;            // [N,N]
  float* adj_hp = out + NN;       // [N,N]
  float* w_lp   = out + 2 * NN;   // [E] (fully overwritten; not zeroed)
  float* w_hp   = w_lp + NEDGES;  // [E] (fully overwritten; not zeroed)
  float* unnorm = w_hp + NEDGES;  // [N,N]

  // ws layout: hash keys/vals first (zeroed), then deg, then small arrays.
  int*   hkeys  = (int*)d_ws;          // [HSLOTS]
  int*   hvals  = hkeys + HSLOTS;      // [HSLOTS]
  float* deg_lp = (float*)(hvals + HSLOTS);  // [N]
  float* deg_hp = deg_lp + NNODES;     // [N]
  float* inv_lp = deg_hp + NNODES;     // [N]
  float* inv_hp = inv_lp + NNODES;     // [N]
  float* g      = inv_hp + NNODES;     // [N]

  // hash (2*HSLOTS ints) + deg (2*N floats) are contiguous: zero together.
  const size_t nc = (2 * (size_t)HSLOTS + 2 * NNODES) / 4;
  zero_kernel<<<8192, 256, 0, stream>>>((float4*)adj_lp, (2 * NN) / 4,
                                        (float4*)unnorm, NN / 4,
                                        (float4*)hkeys, nc);

  embed_g_kernel<<<NNODES / 8, 64, 0, stream>>>(feat, w_emb, b_emb, w_mlp,
                                                b_mlp, g);

  const int eb = NEDGES / 256;  // exact
  edge_weights_kernel<<<eb, 256, 0, stream>>>(edges, g, noise, w_lp, w_hp,
                                              hkeys, hvals);
  edge_deg_kernel<<<eb, 256, 0, stream>>>(edges, w_lp, w_hp, hkeys, hvals,
                                          deg_lp, deg_hp);
  node_inv_kernel<<<(NNODES + 255) / 256, 256, 0, stream>>>(
      deg_lp, deg_hp, inv_lp, inv_hp, adj_lp, adj_hp);
  edge_write_kernel<<<eb, 256, 0, stream>>>(edges, w_lp, w_hp, inv_lp, inv_hp,
                                            hkeys, hvals, adj_lp, adj_hp,
                                            unnorm);
}